// Round 1
// baseline (269.408 us; speedup 1.0000x reference)
//
#include <hip/hip_runtime.h>
#include <hip/hip_bf16.h>

// Sizes (fixed by the problem)
#define B_  32
#define TE_ 8192
#define H_  128
#define M_  (B_ * TE_)   // 262144 rows

typedef __bf16 bf16x8 __attribute__((ext_vector_type(8)));
typedef float  f32x4  __attribute__((ext_vector_type(4)));

__device__ __forceinline__ float tanh_fast(float x) {
  x = fminf(20.f, fmaxf(-20.f, x));
  float e = __expf(2.f * x);
  return (e - 1.f) * __builtin_amdgcn_rcpf(e + 1.f);
}

// ---------------------------------------------------------------------------
// Kernel 1: Uh[b][k] = sum_h dec[b][h] * U[h][k]  (32x128)
//           Wp = W_a packed into bf16 MFMA B-fragment order:
//           idx = ((nt*4+s)*64 + lane)*8 + j  ->  W[(s*32+(lane>>4)*8+j)][nt*16+(lane&15)]
// ---------------------------------------------------------------------------
__global__ __launch_bounds__(256) void prep_kernel(
    const float* __restrict__ dec, const float* __restrict__ U,
    const float* __restrict__ W, float* __restrict__ Uh,
    __bf16* __restrict__ Wp) {
  int tid = blockIdx.x * 256 + threadIdx.x;  // 0..4095
  int b = tid >> 7, k = tid & 127;
  const float* dp = dec + b * H_;
  float s = 0.f;
  #pragma unroll 8
  for (int h = 0; h < H_; ++h) s += dp[h] * U[h * H_ + k];
  Uh[tid] = s;

  for (int i = tid; i < H_ * H_; i += 4096) {
    int j = i & 7;
    int lane = (i >> 3) & 63;
    int f = i >> 9;            // nt*4 + s
    int sK = f & 3, nt = f >> 2;
    int kk = sK * 32 + (lane >> 4) * 8 + j;
    int nn = nt * 16 + (lane & 15);
    Wp[i] = (__bf16)W[kk * H_ + nn];
  }
}

// ---------------------------------------------------------------------------
// Kernel 2: scores[row] = sum_n tanh( (enc[row,:] @ W)[n] + Uh[b][n] ) * V[n]
// bf16 MFMA 16x16x32. Block = 256 threads (4 waves), 256 rows/block.
// Each wave: 4 strips of 16 rows, full N=128 (8 col tiles), K=128 (4 k-steps).
// ---------------------------------------------------------------------------
__global__ __launch_bounds__(256, 4) void score_kernel(
    const float* __restrict__ enc, const float* __restrict__ Uh,
    const float* __restrict__ V, const __bf16* __restrict__ Wp,
    float* __restrict__ scores) {
  __shared__ uint4 ldsW[2048];  // 32 KB packed W (bf16)
  int t = threadIdx.x;
  const uint4* wsrc = (const uint4*)Wp;
  for (int i = t; i < 2048; i += 256) ldsW[i] = wsrc[i];
  __syncthreads();

  int wave = t >> 6, lane = t & 63;
  int l15 = lane & 15, quad = lane >> 4;
  int blockRow = blockIdx.x << 8;        // 256 rows per block; batch-aligned
  int b = blockRow >> 13;                // 8192 rows per batch

  float uh[8], vl[8];
  #pragma unroll
  for (int nt = 0; nt < 8; ++nt) {
    uh[nt] = Uh[b * H_ + nt * 16 + l15];
    vl[nt] = V[nt * 16 + l15];
  }

  for (int it = 0; it < 4; ++it) {
    int rowBase = blockRow + ((it * 4 + wave) << 4);
    const float* rp = enc + (size_t)(rowBase + l15) * H_;

    // A fragments: lane holds A[m=lane&15][k = s*32 + quad*8 + j], j=0..7
    bf16x8 af[4];
    #pragma unroll
    for (int s = 0; s < 4; ++s) {
      const float4* q = (const float4*)(rp + s * 32 + quad * 8);
      float4 lo = q[0], hi = q[1];
      bf16x8 a;
      a[0] = (__bf16)lo.x; a[1] = (__bf16)lo.y; a[2] = (__bf16)lo.z; a[3] = (__bf16)lo.w;
      a[4] = (__bf16)hi.x; a[5] = (__bf16)hi.y; a[6] = (__bf16)hi.z; a[7] = (__bf16)hi.w;
      af[s] = a;
    }

    float p0 = 0.f, p1 = 0.f, p2 = 0.f, p3 = 0.f;
    #pragma unroll
    for (int nt = 0; nt < 8; ++nt) {
      f32x4 acc = {0.f, 0.f, 0.f, 0.f};
      #pragma unroll
      for (int s = 0; s < 4; ++s) {
        union { uint4 u; bf16x8 v; } bw;
        bw.u = ldsW[(nt * 4 + s) * 64 + lane];
        acc = __builtin_amdgcn_mfma_f32_16x16x32_bf16(af[s], bw.v, acc, 0, 0, 0);
      }
      // acc[r]: row = quad*4+r, col = nt*16+l15
      float u = uh[nt], vv = vl[nt];
      p0 += tanh_fast(acc[0] + u) * vv;
      p1 += tanh_fast(acc[1] + u) * vv;
      p2 += tanh_fast(acc[2] + u) * vv;
      p3 += tanh_fast(acc[3] + u) * vv;
    }
    // reduce across the 16 lanes of each quad (cols)
    #pragma unroll
    for (int m = 1; m < 16; m <<= 1) {
      p0 += __shfl_xor(p0, m, 64);
      p1 += __shfl_xor(p1, m, 64);
      p2 += __shfl_xor(p2, m, 64);
      p3 += __shfl_xor(p3, m, 64);
    }
    if (l15 < 4) {
      float v = (l15 == 0) ? p0 : (l15 == 1) ? p1 : (l15 == 2) ? p2 : p3;
      scores[rowBase + quad * 4 + l15] = v;
    }
  }
}

// ---------------------------------------------------------------------------
// Kernel 3: softmax over TE per batch, in place in d_out e_i region.
// Also zeroes the c_i region (runs before context kernel on the stream).
// ---------------------------------------------------------------------------
__global__ __launch_bounds__(1024) void softmax_kernel(
    float* __restrict__ e, float* __restrict__ c) {
  int b = blockIdx.x, t = threadIdx.x;
  if (t < H_) c[b * H_ + t] = 0.f;

  float* p = e + (size_t)b * TE_;
  float4* p4 = (float4*)p;
  float4 v0 = p4[2 * t], v1 = p4[2 * t + 1];

  float m = fmaxf(fmaxf(fmaxf(v0.x, v0.y), fmaxf(v0.z, v0.w)),
                  fmaxf(fmaxf(v1.x, v1.y), fmaxf(v1.z, v1.w)));
  for (int s = 32; s; s >>= 1) m = fmaxf(m, __shfl_xor(m, s, 64));

  __shared__ float redm[16], reds[16];
  int wv = t >> 6, ln = t & 63;
  if (ln == 0) redm[wv] = m;
  __syncthreads();
  if (t == 0) {
    float mm = redm[0];
    for (int i = 1; i < 16; ++i) mm = fmaxf(mm, redm[i]);
    redm[0] = mm;
  }
  __syncthreads();
  float M = redm[0];

  v0.x = __expf(v0.x - M); v0.y = __expf(v0.y - M);
  v0.z = __expf(v0.z - M); v0.w = __expf(v0.w - M);
  v1.x = __expf(v1.x - M); v1.y = __expf(v1.y - M);
  v1.z = __expf(v1.z - M); v1.w = __expf(v1.w - M);

  float s = v0.x + v0.y + v0.z + v0.w + v1.x + v1.y + v1.z + v1.w;
  for (int sh = 32; sh; sh >>= 1) s += __shfl_xor(s, sh, 64);
  if (ln == 0) reds[wv] = s;
  __syncthreads();
  if (t == 0) {
    float ss = 0.f;
    for (int i = 0; i < 16; ++i) ss += reds[i];
    reds[0] = ss;
  }
  __syncthreads();
  float inv = 1.f / reds[0];

  v0.x *= inv; v0.y *= inv; v0.z *= inv; v0.w *= inv;
  v1.x *= inv; v1.y *= inv; v1.z *= inv; v1.w *= inv;
  p4[2 * t] = v0; p4[2 * t + 1] = v1;
}

// ---------------------------------------------------------------------------
// Kernel 4: c[b][h] = sum_e e[b][e] * enc[b][e][h]
// Grid: 32 batches x 8 chunks of 1024 rows. Block 256 = 8 groups x 32 lanes,
// each lane accumulates float4 over 128 rows; LDS reduce; atomicAdd.
// ---------------------------------------------------------------------------
__global__ __launch_bounds__(256) void context_kernel(
    const float* __restrict__ enc, const float* __restrict__ e,
    float* __restrict__ c) {
  int b = blockIdx.x >> 3, chunk = blockIdx.x & 7;
  int t = threadIdx.x;
  int g = t >> 5, lq = t & 31;

  const float* ep = e + (size_t)b * TE_ + chunk * 1024;
  const float4* encp = (const float4*)(enc + ((size_t)b * TE_ + chunk * 1024) * H_);

  float ax = 0.f, ay = 0.f, az = 0.f, aw = 0.f;
  for (int i = 0; i < 128; ++i) {
    int row = i * 8 + g;
    float w = ep[row];
    float4 x = encp[row * 32 + lq];
    ax += w * x.x; ay += w * x.y; az += w * x.z; aw += w * x.w;
  }

  __shared__ float red[8][H_];
  red[g][lq * 4 + 0] = ax;
  red[g][lq * 4 + 1] = ay;
  red[g][lq * 4 + 2] = az;
  red[g][lq * 4 + 3] = aw;
  __syncthreads();
  if (t < H_) {
    float s = 0.f;
    #pragma unroll
    for (int gg = 0; gg < 8; ++gg) s += red[gg][t];
    atomicAdd(&c[b * H_ + t], s);
  }
}

// ---------------------------------------------------------------------------
extern "C" void kernel_launch(void* const* d_in, const int* in_sizes, int n_in,
                              void* d_out, int out_size, void* d_ws, size_t ws_size,
                              hipStream_t stream) {
  const float* enc = (const float*)d_in[0];  // [32, 8192, 128]
  const float* dec = (const float*)d_in[1];  // [32, 1, 128]
  const float* Wa  = (const float*)d_in[2];  // [128, 128]
  const float* Ua  = (const float*)d_in[3];  // [128, 128]
  const float* Va  = (const float*)d_in[4];  // [128, 1]

  float* out   = (float*)d_out;
  float* e_out = out;               // [32][8192] — scores, then e_i in place
  float* c_out = out + B_ * TE_;    // [32][128]

  float*  Uh = (float*)d_ws;                          // 4096 floats (16 KB)
  __bf16* Wp = (__bf16*)((char*)d_ws + 16384);        // 16384 bf16 (32 KB)

  prep_kernel<<<16, 256, 0, stream>>>(dec, Ua, Wa, Uh, Wp);
  score_kernel<<<M_ / 256, 256, 0, stream>>>(enc, Uh, Va, Wp, e_out);
  softmax_kernel<<<B_, 1024, 0, stream>>>(e_out, c_out);
  context_kernel<<<B_ * 8, 256, 0, stream>>>(enc, e_out, c_out);
}

// Round 2
// 220.788 us; speedup vs baseline: 1.2202x; 1.2202x over previous
//
#include <hip/hip_runtime.h>
#include <hip/hip_bf16.h>

// Sizes (fixed by the problem)
#define B_  32
#define TE_ 8192
#define H_  128
#define M_  (B_ * TE_)   // 262144 rows

typedef __bf16 bf16x8 __attribute__((ext_vector_type(8)));
typedef float  f32x4  __attribute__((ext_vector_type(4)));

// ws layout (floats): Uh[4096] | Wp(16384 bf16 = 8192 float slots) | Lacc[32] | Cacc[4096]
#define WS_UH    0
#define WS_WP    4096
#define WS_LACC  (4096 + 8192)
#define WS_CACC  (WS_LACC + 32)

__device__ __forceinline__ float tanh_fast(float x) {
  x = fminf(10.f, fmaxf(-10.f, x));
  float e = __expf(2.f * x);
  return (e - 1.f) * __builtin_amdgcn_rcpf(e + 1.f);
}

// ---------------------------------------------------------------------------
// Kernel 1: Uh = dec @ U (32x128); pack W into bf16 MFMA B-fragment order;
// zero the Lacc / Cacc accumulators (ws is poisoned 0xAA each launch).
// ---------------------------------------------------------------------------
__global__ __launch_bounds__(256) void prep_kernel(
    const float* __restrict__ dec, const float* __restrict__ U,
    const float* __restrict__ W, float* __restrict__ ws) {
  int tid = blockIdx.x * 256 + threadIdx.x;  // 0..4095
  int b = tid >> 7, k = tid & 127;
  const float* dp = dec + b * H_;
  float s = 0.f;
  #pragma unroll 8
  for (int h = 0; h < H_; ++h) s += dp[h] * U[h * H_ + k];
  ws[WS_UH + tid] = s;

  ws[WS_CACC + tid] = 0.f;
  if (tid < 32) ws[WS_LACC + tid] = 0.f;

  __bf16* Wp = (__bf16*)(ws + WS_WP);
  for (int i = tid; i < H_ * H_; i += 4096) {
    int j = i & 7;
    int lane = (i >> 3) & 63;
    int f = i >> 9;            // nt*4 + s
    int sK = f & 3, nt = f >> 2;
    int kk = sK * 32 + (lane >> 4) * 8 + j;
    int nn = nt * 16 + (lane & 15);
    Wp[i] = (__bf16)W[kk * H_ + nn];
  }
}

// ---------------------------------------------------------------------------
// Kernel 2 (fused): per 256-row block:
//   score -> w = exp(score) (no max needed: |score| <= ||V||_1 ~ 5)
//   store w (unnormalized) to e region; accumulate per-batch L = sum w and
//   partial context C = sum w * enc via LDS reduce + atomicAdd.
// Software-pipelined: next strip's 8 global loads issued right after bf16
// pack, in flight across the MFMA + tanh epilogue.
// ---------------------------------------------------------------------------
__global__ __launch_bounds__(256, 4) void fused_kernel(
    const float* __restrict__ enc, const float* __restrict__ ws_in,
    const float* __restrict__ V, float* __restrict__ wout,
    float* __restrict__ ws) {
  __shared__ uint4 ldsW[2048];      // 32 KB packed W (bf16)
  __shared__ float pcbuf[4][H_];    // per-wave partial context
  __shared__ float lsum[4];

  int t = threadIdx.x;
  const uint4* wsrc = (const uint4*)(ws_in + WS_WP);
  for (int i = t; i < 2048; i += 256) ldsW[i] = wsrc[i];

  int wave = t >> 6, lane = t & 63;
  int l15 = lane & 15, quad = lane >> 4;
  int blockRow = blockIdx.x << 8;   // 256 rows/block, batch-aligned
  int b = blockRow >> 13;

  float uh[8], vl[8];
  #pragma unroll
  for (int nt = 0; nt < 8; ++nt) {
    uh[nt] = ws_in[WS_UH + b * H_ + nt * 16 + l15];
    vl[nt] = V[nt * 16 + l15];
  }
  __syncthreads();

  float cacc[32];
  #pragma unroll
  for (int k = 0; k < 32; ++k) cacc[k] = 0.f;
  float Lpart = 0.f;

  // strip row pointer: rows blockRow + (it*4+wave)*16 + l15
  const float4* rp0 = (const float4*)(enc + (size_t)(blockRow + (wave << 4) + l15) * H_) + quad * 2;
  const int stripStride = 4 * 16 * (H_ / 4);  // 4 strips apart * 16 rows * 32 float4

  float4 buf[8];
  #pragma unroll
  for (int s = 0; s < 4; ++s) {
    buf[2 * s]     = rp0[s * 8];
    buf[2 * s + 1] = rp0[s * 8 + 1];
  }

  #pragma unroll
  for (int it = 0; it < 4; ++it) {
    // pack current strip to bf16 A-fragments (waits on buf's loads)
    bf16x8 af[4];
    #pragma unroll
    for (int s = 0; s < 4; ++s) {
      float4 lo = buf[2 * s], hi = buf[2 * s + 1];
      bf16x8 a;
      a[0] = (__bf16)lo.x; a[1] = (__bf16)lo.y; a[2] = (__bf16)lo.z; a[3] = (__bf16)lo.w;
      a[4] = (__bf16)hi.x; a[5] = (__bf16)hi.y; a[6] = (__bf16)hi.z; a[7] = (__bf16)hi.w;
      af[s] = a;
    }
    // prefetch next strip (in flight across MFMA + epilogue)
    if (it < 3) {
      const float4* rp = rp0 + (it + 1) * stripStride;
      #pragma unroll
      for (int s = 0; s < 4; ++s) {
        buf[2 * s]     = rp[s * 8];
        buf[2 * s + 1] = rp[s * 8 + 1];
      }
    }

    float p0 = 0.f, p1 = 0.f, p2 = 0.f, p3 = 0.f;
    #pragma unroll
    for (int nt = 0; nt < 8; ++nt) {
      f32x4 acc = {0.f, 0.f, 0.f, 0.f};
      #pragma unroll
      for (int s = 0; s < 4; ++s) {
        union { uint4 u; bf16x8 v; } bw;
        bw.u = ldsW[(nt * 4 + s) * 64 + lane];
        acc = __builtin_amdgcn_mfma_f32_16x16x32_bf16(af[s], bw.v, acc, 0, 0, 0);
      }
      float u = uh[nt], vv = vl[nt];
      p0 += tanh_fast(acc[0] + u) * vv;
      p1 += tanh_fast(acc[1] + u) * vv;
      p2 += tanh_fast(acc[2] + u) * vv;
      p3 += tanh_fast(acc[3] + u) * vv;
    }
    // reduce over the 16 l15 lanes of each quad (stays within quad)
    #pragma unroll
    for (int m = 1; m < 16; m <<= 1) {
      p0 += __shfl_xor(p0, m, 64);
      p1 += __shfl_xor(p1, m, 64);
      p2 += __shfl_xor(p2, m, 64);
      p3 += __shfl_xor(p3, m, 64);
    }
    // unnormalized softmax weights for rows quad*4 + {0..3}
    float w0 = __expf(p0), w1 = __expf(p1), w2 = __expf(p2), w3 = __expf(p3);
    int rowBase = blockRow + ((it * 4 + wave) << 4);
    if (l15 < 4) {
      float v = (l15 == 0) ? w0 : (l15 == 1) ? w1 : (l15 == 2) ? w2 : w3;
      wout[rowBase + quad * 4 + l15] = v;
    }
    Lpart += w0 + w1 + w2 + w3;  // uniform within quad

    // weight for THIS lane's A-fragment row (row = l15): lives in quad l15>>2
    int srcLane = (l15 >> 2) << 4;
    float q0 = __shfl(w0, srcLane, 64);
    float q1 = __shfl(w1, srcLane, 64);
    float q2 = __shfl(w2, srcLane, 64);
    float q3 = __shfl(w3, srcLane, 64);
    int r = l15 & 3;
    float wrow = (r == 0) ? q0 : (r == 1) ? q1 : (r == 2) ? q2 : q3;

    // context: cacc[s*8+j] += wrow * enc[row=l15][col=s*32+quad*8+j]
    #pragma unroll
    for (int s = 0; s < 4; ++s) {
      #pragma unroll
      for (int j = 0; j < 8; ++j)
        cacc[s * 8 + j] += wrow * (float)af[s][j];
    }
  }

  // reduce context over the 16 rows (l15 lanes) of each quad
  #pragma unroll
  for (int m = 1; m < 16; m <<= 1) {
    #pragma unroll
    for (int k = 0; k < 32; ++k)
      cacc[k] += __shfl_xor(cacc[k], m, 64);
  }
  if (l15 == 0) {
    #pragma unroll
    for (int s = 0; s < 4; ++s)
      #pragma unroll
      for (int j = 0; j < 8; ++j)
        pcbuf[wave][s * 32 + quad * 8 + j] = cacc[s * 8 + j];
  }
  // L: uniform within quad; sum across quads
  Lpart += __shfl_xor(Lpart, 16, 64);
  Lpart += __shfl_xor(Lpart, 32, 64);
  if (lane == 0) lsum[wave] = Lpart;
  __syncthreads();

  if (t < H_) {
    float s = pcbuf[0][t] + pcbuf[1][t] + pcbuf[2][t] + pcbuf[3][t];
    atomicAdd(&ws[WS_CACC + b * H_ + t], s);
  }
  if (t == 0)
    atomicAdd(&ws[WS_LACC + b], lsum[0] + lsum[1] + lsum[2] + lsum[3]);
}

// ---------------------------------------------------------------------------
// Kernel 3: normalize. Blocks 0..255: e = w / L (float4). Block 256: c = C / L.
// ---------------------------------------------------------------------------
__global__ __launch_bounds__(256) void finalize_kernel(
    float* __restrict__ e, float* __restrict__ c, const float* __restrict__ ws) {
  int t = threadIdx.x;
  if (blockIdx.x < 256) {
    int i4 = blockIdx.x * 256 + t;     // 65536 float4 total
    int b = i4 >> 11;                  // 2048 float4 per batch
    float inv = 1.f / ws[WS_LACC + b];
    float4 v = ((float4*)e)[i4];
    v.x *= inv; v.y *= inv; v.z *= inv; v.w *= inv;
    ((float4*)e)[i4] = v;
  } else {
    #pragma unroll
    for (int k = 0; k < 16; ++k) {
      int i = k * 256 + t;             // 0..4095
      int b = i >> 7;
      c[i] = ws[WS_CACC + i] / ws[WS_LACC + b];
    }
  }
}

// ---------------------------------------------------------------------------
extern "C" void kernel_launch(void* const* d_in, const int* in_sizes, int n_in,
                              void* d_out, int out_size, void* d_ws, size_t ws_size,
                              hipStream_t stream) {
  const float* enc = (const float*)d_in[0];  // [32, 8192, 128]
  const float* dec = (const float*)d_in[1];  // [32, 1, 128]
  const float* Wa  = (const float*)d_in[2];  // [128, 128]
  const float* Ua  = (const float*)d_in[3];  // [128, 128]
  const float* Va  = (const float*)d_in[4];  // [128, 1]

  float* out   = (float*)d_out;
  float* e_out = out;               // [32][8192]
  float* c_out = out + B_ * TE_;    // [32][128]
  float* ws    = (float*)d_ws;

  prep_kernel<<<16, 256, 0, stream>>>(dec, Ua, Wa, ws);
  fused_kernel<<<M_ / 256, 256, 0, stream>>>(enc, ws, Va, e_out, ws);
  finalize_kernel<<<257, 256, 0, stream>>>(e_out, c_out, ws);
}

// Round 3
// 210.706 us; speedup vs baseline: 1.2786x; 1.0478x over previous
//
#include <hip/hip_runtime.h>
#include <hip/hip_bf16.h>

// Sizes (fixed by the problem)
#define B_  32
#define TE_ 8192
#define H_  128
#define M_  (B_ * TE_)   // 262144 rows

typedef __bf16 bf16x8 __attribute__((ext_vector_type(8)));
typedef float  f32x4  __attribute__((ext_vector_type(4)));

// ws layout (floats): Uh[4096] | Wp(16384 bf16 = 8192 float slots) | Lacc[32] | Cacc[4096]
#define WS_UH    0
#define WS_WP    4096
#define WS_LACC  (4096 + 8192)
#define WS_CACC  (WS_LACC + 32)

__device__ __forceinline__ float tanh_fast(float x) {
  x = fminf(10.f, fmaxf(-10.f, x));
  float e = __expf(2.f * x);
  return (e - 1.f) * __builtin_amdgcn_rcpf(e + 1.f);
}

// ---------------------------------------------------------------------------
// Kernel 1: Uh = dec @ U (32x128); pack W into bf16 MFMA fragment order
// (frag idx ((nt*4+s)*64+lane)*8+j -> W[s*32+quad*8+j][nt*16+l15]; this same
// packing serves as the A-operand of the transposed product W^T * enc^T).
// Zero Lacc/Cacc (ws is poisoned 0xAA before every launch).
// ---------------------------------------------------------------------------
__global__ __launch_bounds__(256) void prep_kernel(
    const float* __restrict__ dec, const float* __restrict__ U,
    const float* __restrict__ W, float* __restrict__ ws) {
  int tid = blockIdx.x * 256 + threadIdx.x;  // 0..4095
  int b = tid >> 7, k = tid & 127;
  const float* dp = dec + b * H_;
  float s = 0.f;
  #pragma unroll 8
  for (int h = 0; h < H_; ++h) s += dp[h] * U[h * H_ + k];
  ws[WS_UH + tid] = s;

  ws[WS_CACC + tid] = 0.f;
  if (tid < 32) ws[WS_LACC + tid] = 0.f;

  __bf16* Wp = (__bf16*)(ws + WS_WP);
  for (int i = tid; i < H_ * H_; i += 4096) {
    int j = i & 7;
    int lane = (i >> 3) & 63;
    int f = i >> 9;            // nt*4 + s
    int sK = f & 3, nt = f >> 2;
    int kk = sK * 32 + ((lane >> 4) & 3) * 8 + j;
    int nn = nt * 16 + (lane & 15);
    Wp[i] = (__bf16)W[kk * H_ + nn];
  }
}

// ---------------------------------------------------------------------------
// Kernel 2 (fused, transposed MFMA): per 256-row block:
//   D = W^T * enc^T  -> each lane's acc holds score components for its OWN
//   row (l15) at score-dims nt*16+quad*4+r. Reduce = 2 shfl_xor (quad bits),
//   1 exp/lane/strip, contiguous score store, no broadcast for context.
//   w = exp(score) (safe: |score| <= ||V||_1 ~ 5). Accumulate per-batch
//   L = sum w and partial context C = sum w*enc; atomicAdd at block end.
// enc loads are nontemporal (single-use stream; keeps Wp/u/v hot in L3 and
// avoids flushing the harness's dirty poison lines).
// ---------------------------------------------------------------------------
__global__ __launch_bounds__(256, 4) void fused_kernel(
    const float* __restrict__ enc, const float* __restrict__ ws_in,
    const float* __restrict__ V, float* __restrict__ wout,
    float* __restrict__ ws) {
  __shared__ uint4 ldsW[2048];      // 32 KB packed W; reused as pcbuf at end
  __shared__ float ldsUV[256];      // u[128] | v[128]
  __shared__ float lsum[4];

  int t = threadIdx.x;
  int blockRow = blockIdx.x << 8;   // 256 rows/block, batch-aligned
  int b = blockRow >> 13;

  const uint4* wsrc = (const uint4*)(ws_in + WS_WP);
  for (int i = t; i < 2048; i += 256) ldsW[i] = wsrc[i];
  if (t < 128) ldsUV[t] = ws_in[WS_UH + b * H_ + t];
  else ldsUV[t] = V[t - 128];
  __syncthreads();

  int wave = t >> 6, lane = t & 63;
  int l15 = lane & 15, quad = lane >> 4;

  float cacc[32];
  #pragma unroll
  for (int k = 0; k < 32; ++k) cacc[k] = 0.f;
  float Lpart = 0.f;

  // strip rows: blockRow + (it*4+wave)*16 + l15 ; this lane reads its row's
  // bytes [quad*32 + s*128, +16) and [+16,+32) per s.
  const f32x4* rp0 = (const f32x4*)(enc + (size_t)(blockRow + (wave << 4) + l15) * H_) + quad * 2;
  const int stripStride = 4 * 16 * (H_ / 4);  // 2048 float4 = 64 rows

  f32x4 buf[8];
  #pragma unroll
  for (int s = 0; s < 4; ++s) {
    buf[2 * s]     = __builtin_nontemporal_load(rp0 + s * 8);
    buf[2 * s + 1] = __builtin_nontemporal_load(rp0 + s * 8 + 1);
  }

  #pragma unroll
  for (int it = 0; it < 4; ++it) {
    // pack current strip to bf16 fragments (lane = enc row l15)
    bf16x8 af[4];
    #pragma unroll
    for (int s = 0; s < 4; ++s) {
      f32x4 lo = buf[2 * s], hi = buf[2 * s + 1];
      bf16x8 a;
      a[0] = (__bf16)lo[0]; a[1] = (__bf16)lo[1]; a[2] = (__bf16)lo[2]; a[3] = (__bf16)lo[3];
      a[4] = (__bf16)hi[0]; a[5] = (__bf16)hi[1]; a[6] = (__bf16)hi[2]; a[7] = (__bf16)hi[3];
      af[s] = a;
    }
    // prefetch next strip (in flight across MFMA + epilogue)
    if (it < 3) {
      const f32x4* rp = rp0 + (it + 1) * stripStride;
      #pragma unroll
      for (int s = 0; s < 4; ++s) {
        buf[2 * s]     = __builtin_nontemporal_load(rp + s * 8);
        buf[2 * s + 1] = __builtin_nontemporal_load(rp + s * 8 + 1);
      }
    }

    float p = 0.f;
    #pragma unroll
    for (int nt = 0; nt < 8; ++nt) {
      f32x4 acc = {0.f, 0.f, 0.f, 0.f};
      #pragma unroll
      for (int s = 0; s < 4; ++s) {
        union { uint4 u; bf16x8 v; } bw;
        bw.u = ldsW[(nt * 4 + s) * 64 + lane];
        // A = W^T tile (m = score-dim), B = enc (n = row)
        acc = __builtin_amdgcn_mfma_f32_16x16x32_bf16(bw.v, af[s], acc, 0, 0, 0);
      }
      // acc[r] = score-component at n_glob = nt*16 + quad*4 + r, for row l15
      float4 u4 = ((const float4*)ldsUV)[nt * 4 + quad];          // quad-uniform broadcast
      float4 v4 = ((const float4*)(ldsUV + 128))[nt * 4 + quad];
      p += tanh_fast(acc[0] + u4.x) * v4.x;
      p += tanh_fast(acc[1] + u4.y) * v4.y;
      p += tanh_fast(acc[2] + u4.z) * v4.z;
      p += tanh_fast(acc[3] + u4.w) * v4.w;
    }
    // sum the 4 quads (same l15) -> full score for row l15 in every lane
    p += __shfl_xor(p, 16, 64);
    p += __shfl_xor(p, 32, 64);
    float w = __expf(p);

    int rowBase = blockRow + ((it * 4 + wave) << 4);
    if (quad == 0) wout[rowBase + l15] = w;   // contiguous 64B line per wave
    Lpart += w;                                // quads duplicate; l15 distinct

    // context: this lane's af row IS row l15 -> weight is w directly
    #pragma unroll
    for (int s = 0; s < 4; ++s)
      #pragma unroll
      for (int j = 0; j < 8; ++j)
        cacc[s * 8 + j] += w * (float)af[s][j];
  }

  // reduce context over the 16 rows (l15 lanes) of each quad
  #pragma unroll
  for (int m = 1; m < 16; m <<= 1) {
    #pragma unroll
    for (int k = 0; k < 32; ++k)
      cacc[k] += __shfl_xor(cacc[k], m, 64);
  }
  // L: butterfly over l15 bits only (quads hold identical copies)
  Lpart += __shfl_xor(Lpart, 1, 64);
  Lpart += __shfl_xor(Lpart, 2, 64);
  Lpart += __shfl_xor(Lpart, 4, 64);
  Lpart += __shfl_xor(Lpart, 8, 64);

  __syncthreads();                   // all ldsW reads done; reuse as pcbuf
  float* pcbuf = (float*)ldsW;       // [4][128]
  if (l15 == 0) {
    #pragma unroll
    for (int s = 0; s < 4; ++s)
      #pragma unroll
      for (int j = 0; j < 8; ++j)
        pcbuf[wave * H_ + s * 32 + quad * 8 + j] = cacc[s * 8 + j];
  }
  if (lane == 0) lsum[wave] = Lpart;
  __syncthreads();

  if (t < H_) {
    float s = pcbuf[0 * H_ + t] + pcbuf[1 * H_ + t] + pcbuf[2 * H_ + t] + pcbuf[3 * H_ + t];
    atomicAdd(&ws[WS_CACC + b * H_ + t], s);
  }
  if (t == 0)
    atomicAdd(&ws[WS_LACC + b], lsum[0] + lsum[1] + lsum[2] + lsum[3]);
}

// ---------------------------------------------------------------------------
// Kernel 3: normalize. Blocks 0..255: e = w / L (float4). Block 256: c = C / L.
// ---------------------------------------------------------------------------
__global__ __launch_bounds__(256) void finalize_kernel(
    float* __restrict__ e, float* __restrict__ c, const float* __restrict__ ws) {
  int t = threadIdx.x;
  if (blockIdx.x < 256) {
    int i4 = blockIdx.x * 256 + t;     // 65536 float4 total
    int b = i4 >> 11;                  // 2048 float4 per batch
    float inv = 1.f / ws[WS_LACC + b];
    float4 v = ((float4*)e)[i4];
    v.x *= inv; v.y *= inv; v.z *= inv; v.w *= inv;
    ((float4*)e)[i4] = v;
  } else {
    #pragma unroll
    for (int k = 0; k < 16; ++k) {
      int i = k * 256 + t;             // 0..4095
      int b = i >> 7;
      c[i] = ws[WS_CACC + i] / ws[WS_LACC + b];
    }
  }
}

// ---------------------------------------------------------------------------
extern "C" void kernel_launch(void* const* d_in, const int* in_sizes, int n_in,
                              void* d_out, int out_size, void* d_ws, size_t ws_size,
                              hipStream_t stream) {
  const float* enc = (const float*)d_in[0];  // [32, 8192, 128]
  const float* dec = (const float*)d_in[1];  // [32, 1, 128]
  const float* Wa  = (const float*)d_in[2];  // [128, 128]
  const float* Ua  = (const float*)d_in[3];  // [128, 128]
  const float* Va  = (const float*)d_in[4];  // [128, 1]

  float* out   = (float*)d_out;
  float* e_out = out;               // [32][8192]
  float* c_out = out + B_ * TE_;    // [32][128]
  float* ws    = (float*)d_ws;

  prep_kernel<<<16, 256, 0, stream>>>(dec, Ua, Wa, ws);
  fused_kernel<<<M_ / 256, 256, 0, stream>>>(enc, ws, Va, e_out, ws);
  finalize_kernel<<<257, 256, 0, stream>>>(e_out, c_out, ws);
}

// Round 5
// 204.851 us; speedup vs baseline: 1.3151x; 1.0286x over previous
//
#include <hip/hip_runtime.h>
#include <hip/hip_bf16.h>

// Sizes (fixed by the problem)
#define B_  32
#define TE_ 8192
#define H_  128
#define M_  (B_ * TE_)   // 262144 rows

typedef __bf16 bf16x8 __attribute__((ext_vector_type(8)));
typedef __bf16 bf16x4 __attribute__((ext_vector_type(4)));
typedef float  f32x4  __attribute__((ext_vector_type(4)));

// ws layout (floats): Uh[4096] | Wp(16384 bf16 = 8192 float slots) | Lacc[32] | Cacc[4096]
#define WS_UH    0
#define WS_WP    4096
#define WS_LACC  (4096 + 8192)
#define WS_CACC  (WS_LACC + 32)

// LDS strip buffer: 16 rows x 256 B (bf16 row) + 16 B pad -> 272 B row stride
#define SROW 272

__device__ __forceinline__ float tanh_fast(float x) {
  x = fminf(10.f, fmaxf(-10.f, x));
  float e = __expf(2.f * x);
  return (e - 1.f) * __builtin_amdgcn_rcpf(e + 1.f);
}

// ---------------------------------------------------------------------------
// Kernel 1 (32 blocks): block b computes Uh[b][:] (U staged in LDS, coalesced),
// zeros its slice of Lacc/Cacc, and packs W fragment-group f=b into ws.
// Wp order: element ((f*64+lane)*8+j) = W[sK*32+((lane>>4)&3)*8+j][nt*16+(lane&15)],
// f = nt*4+sK.  NOTE: packs from global W (R4 bug: read ldsU == U_a instead).
// ---------------------------------------------------------------------------
__global__ __launch_bounds__(256) void prep_kernel(
    const float* __restrict__ dec, const float* __restrict__ U,
    const float* __restrict__ W, float* __restrict__ ws) {
  __shared__ float ldsU[H_ * H_];   // 64 KB (holds U_a for the Uh dot-product)
  __shared__ float ldsd[H_];
  int b = blockIdx.x, t = threadIdx.x;

  float4* l4 = (float4*)ldsU;
  const float4* g4 = (const float4*)U;
  #pragma unroll
  for (int i = 0; i < 16; ++i) l4[t + 256 * i] = g4[t + 256 * i];
  if (t < 32) ((float4*)ldsd)[t] = ((const float4*)(dec + b * H_))[t];
  __syncthreads();

  if (t < H_) {
    float s = 0.f;
    #pragma unroll
    for (int h = 0; h < H_; ++h) s += ldsd[h] * ldsU[h * H_ + t];
    ws[WS_UH + b * H_ + t] = s;
    ws[WS_CACC + b * H_ + t] = 0.f;
  }
  if (t == 0) ws[WS_LACC + b] = 0.f;

  if (t < 64) {
    int nt = b >> 2, sK = b & 3;
    int kk0 = sK * 32 + ((t >> 4) & 3) * 8;
    int nn = nt * 16 + (t & 15);
    __bf16* Wp = (__bf16*)(ws + WS_WP);
    #pragma unroll
    for (int j = 0; j < 8; ++j)
      Wp[(b * 64 + t) * 8 + j] = (__bf16)W[(kk0 + j) * H_ + nn];   // <-- W, not ldsU
  }
}

// ---------------------------------------------------------------------------
// Kernel 2 (fused): per 256-row block, 4 waves x 4 strips of 16 rows.
// Per strip: lane-contiguous nontemporal float4 loads (addr = base + lane*16,
// 8 fully-used 128B lines per instruction) -> cvt bf16 -> LDS scatter
// (272B row stride, conflict-free) -> ds_read_b128 MFMA fragments.
// D = W^T * enc^T: each lane holds its own row's (l15) score components;
// reduce = 2 quad shfl_xor, 1 exp. w = exp(score) is safe (|score|<=||V||1~5).
// Accumulate per-batch L and partial context C; atomicAdd at block end.
// ---------------------------------------------------------------------------
__global__ __launch_bounds__(256, 3) void fused_kernel(
    const float* __restrict__ enc, const float* __restrict__ ws_in,
    const float* __restrict__ V, float* __restrict__ wout,
    float* __restrict__ ws) {
  __shared__ uint4 ldsW[2048];      // 32 KB packed W; reused as pcbuf at end
  __shared__ float ldsUV[256];      // u[128] | v[128]
  __shared__ float lsum[4];
  __shared__ __align__(16) unsigned char ldsS[4][16 * SROW];  // 17 KB strips

  int t = threadIdx.x, wave = t >> 6, lane = t & 63;
  int l15 = lane & 15, quad = lane >> 4;
  int blockRow = blockIdx.x << 8;   // 256 rows/block, batch-aligned
  int b = blockRow >> 13;

  // issue strip-0 enc loads FIRST (in flight across the W-LDS fill)
  const char* gbase = (const char*)enc + (size_t)(blockRow + (wave << 4)) * (H_ * 4);
  f32x4 ld[8];
  #pragma unroll
  for (int i = 0; i < 8; ++i)
    ld[i] = __builtin_nontemporal_load((const f32x4*)(gbase + i * 1024 + lane * 16));

  const uint4* wsrc = (const uint4*)(ws_in + WS_WP);
  for (int i = t; i < 2048; i += 256) ldsW[i] = wsrc[i];
  if (t < 128) ldsUV[t] = ws_in[WS_UH + b * H_ + t];
  else ldsUV[t] = V[t - 128];
  __syncthreads();

  float cacc[32];
  #pragma unroll
  for (int k = 0; k < 32; ++k) cacc[k] = 0.f;
  float Lpart = 0.f;

  unsigned char* sb = ldsS[wave];
  int wrhi = lane >> 5, wc = lane & 31;   // write row parity / 8B-chunk

  #pragma unroll
  for (int it = 0; it < 4; ++it) {
    // cvt current strip to bf16 (waits on its loads)
    uint2 hp[8];
    #pragma unroll
    for (int i = 0; i < 8; ++i) {
      union { bf16x4 h; uint2 u; } cv;
      cv.h[0] = (__bf16)ld[i][0]; cv.h[1] = (__bf16)ld[i][1];
      cv.h[2] = (__bf16)ld[i][2]; cv.h[3] = (__bf16)ld[i][3];
      hp[i] = cv.u;
    }
    // issue next strip's loads (in flight across LDS + MFMA + epilogue)
    if (it < 3) {
      #pragma unroll
      for (int i = 0; i < 8; ++i)
        ld[i] = __builtin_nontemporal_load(
            (const f32x4*)(gbase + (it + 1) * 32768 + i * 1024 + lane * 16));
    }
    // scatter to LDS: piece i = row 2i+wrhi, bytes [wc*8, wc*8+8)
    #pragma unroll
    for (int i = 0; i < 8; ++i)
      *(uint2*)(sb + (2 * i + wrhi) * SROW + wc * 8) = hp[i];

    // read MFMA B-fragments: af[s] = row l15, cols s*32+quad*8..+7 (bf16)
    bf16x8 af[4];
    #pragma unroll
    for (int s = 0; s < 4; ++s)
      af[s] = *(const bf16x8*)(sb + l15 * SROW + s * 64 + quad * 16);

    float p = 0.f;
    #pragma unroll
    for (int nt = 0; nt < 8; ++nt) {
      f32x4 acc = {0.f, 0.f, 0.f, 0.f};
      #pragma unroll
      for (int s = 0; s < 4; ++s) {
        union { uint4 u; bf16x8 v; } bw;
        bw.u = ldsW[(nt * 4 + s) * 64 + lane];
        acc = __builtin_amdgcn_mfma_f32_16x16x32_bf16(bw.v, af[s], acc, 0, 0, 0);
      }
      float4 u4 = ((const float4*)ldsUV)[nt * 4 + quad];
      float4 v4 = ((const float4*)(ldsUV + 128))[nt * 4 + quad];
      p += tanh_fast(acc[0] + u4.x) * v4.x;
      p += tanh_fast(acc[1] + u4.y) * v4.y;
      p += tanh_fast(acc[2] + u4.z) * v4.z;
      p += tanh_fast(acc[3] + u4.w) * v4.w;
    }
    // sum the 4 quads -> full score for row l15 in every lane
    p += __shfl_xor(p, 16, 64);
    p += __shfl_xor(p, 32, 64);
    float w = __expf(p);

    int rowBase = blockRow + ((it * 4 + wave) << 4);
    if (quad == 0) wout[rowBase + l15] = w;   // contiguous 64B line
    Lpart += w;                                // l15 distinct; quads duplicate

    // context: this lane's af row IS row l15 -> weight is w directly
    #pragma unroll
    for (int s = 0; s < 4; ++s)
      #pragma unroll
      for (int j = 0; j < 8; ++j)
        cacc[s * 8 + j] += w * (float)af[s][j];
  }

  // reduce context over the 16 rows (l15 lanes) of each quad
  #pragma unroll
  for (int m = 1; m < 16; m <<= 1) {
    #pragma unroll
    for (int k = 0; k < 32; ++k)
      cacc[k] += __shfl_xor(cacc[k], m, 64);
  }
  // L: reduce over l15 bits (quads hold identical copies)
  Lpart += __shfl_xor(Lpart, 1, 64);
  Lpart += __shfl_xor(Lpart, 2, 64);
  Lpart += __shfl_xor(Lpart, 4, 64);
  Lpart += __shfl_xor(Lpart, 8, 64);

  __syncthreads();                   // all ldsW reads done; reuse as pcbuf
  float* pcbuf = (float*)ldsW;       // [4][128]
  if (l15 == 0) {
    #pragma unroll
    for (int s = 0; s < 4; ++s)
      #pragma unroll
      for (int j = 0; j < 8; ++j)
        pcbuf[wave * H_ + s * 32 + quad * 8 + j] = cacc[s * 8 + j];
  }
  if (lane == 0) lsum[wave] = Lpart;
  __syncthreads();

  if (t < H_) {
    float s = pcbuf[0 * H_ + t] + pcbuf[1 * H_ + t] + pcbuf[2 * H_ + t] + pcbuf[3 * H_ + t];
    atomicAdd(&ws[WS_CACC + b * H_ + t], s);
  }
  if (t == 0)
    atomicAdd(&ws[WS_LACC + b], lsum[0] + lsum[1] + lsum[2] + lsum[3]);
}

// ---------------------------------------------------------------------------
// Kernel 3: normalize. Blocks 0..255: e = w / L (float4). Block 256: c = C / L.
// ---------------------------------------------------------------------------
__global__ __launch_bounds__(256) void finalize_kernel(
    float* __restrict__ e, float* __restrict__ c, const float* __restrict__ ws) {
  int t = threadIdx.x;
  if (blockIdx.x < 256) {
    int i4 = blockIdx.x * 256 + t;     // 65536 float4 total
    int b = i4 >> 11;                  // 2048 float4 per batch
    float inv = 1.f / ws[WS_LACC + b];
    float4 v = ((float4*)e)[i4];
    v.x *= inv; v.y *= inv; v.z *= inv; v.w *= inv;
    ((float4*)e)[i4] = v;
  } else {
    #pragma unroll
    for (int k = 0; k < 16; ++k) {
      int i = k * 256 + t;             // 0..4095
      int b = i >> 7;
      c[i] = ws[WS_CACC + i] / ws[WS_LACC + b];
    }
  }
}

// ---------------------------------------------------------------------------
extern "C" void kernel_launch(void* const* d_in, const int* in_sizes, int n_in,
                              void* d_out, int out_size, void* d_ws, size_t ws_size,
                              hipStream_t stream) {
  const float* enc = (const float*)d_in[0];  // [32, 8192, 128]
  const float* dec = (const float*)d_in[1];  // [32, 1, 128]
  const float* Wa  = (const float*)d_in[2];  // [128, 128]
  const float* Ua  = (const float*)d_in[3];  // [128, 128]
  const float* Va  = (const float*)d_in[4];  // [128, 1]

  float* out   = (float*)d_out;
  float* e_out = out;               // [32][8192]
  float* c_out = out + B_ * TE_;    // [32][128]
  float* ws    = (float*)d_ws;

  prep_kernel<<<B_, 256, 0, stream>>>(dec, Ua, Wa, ws);
  fused_kernel<<<M_ / 256, 256, 0, stream>>>(enc, ws, Va, e_out, ws);
  finalize_kernel<<<257, 256, 0, stream>>>(e_out, c_out, ws);
}